// Round 5
// baseline (359.311 us; speedup 1.0000x reference)
//
#include <hip/hip_runtime.h>
#include <math.h>

#define LOG2E 1.4426950408889634f

typedef __attribute__((ext_vector_type(8))) __bf16 bf16x8_t;
typedef __attribute__((ext_vector_type(8))) short short8_t;
typedef __attribute__((ext_vector_type(4))) float f32x4;

static __device__ __forceinline__ short f2bf(float f){
    unsigned u = __builtin_bit_cast(unsigned, f);
    unsigned r = (u + 0x7fffu + ((u >> 16) & 1u)) >> 16;
    return (short)r;
}

static __device__ __forceinline__ f32x4 mfma16(short8_t a, short8_t b, f32x4 c){
    return __builtin_amdgcn_mfma_f32_16x16x32_bf16(
        __builtin_bit_cast(bf16x8_t, a), __builtin_bit_cast(bf16x8_t, b), c, 0, 0, 0);
}

// DPP row-rotate (within 16-lane row) — VALU pipe.
template<int CTRL>
static __device__ __forceinline__ float dppmov(float v){
    return __builtin_bit_cast(float, __builtin_amdgcn_update_dpp(
        0, __builtin_bit_cast(int, v), CTRL, 0xF, 0xF, true));
}
static __device__ __forceinline__ void rowred_max(f32x4& v){
    #pragma unroll
    for (int r = 0; r < 4; r++){
        float t = v[r];
        t = fmaxf(t, dppmov<0x121>(t));
        t = fmaxf(t, dppmov<0x122>(t));
        t = fmaxf(t, dppmov<0x124>(t));
        t = fmaxf(t, dppmov<0x128>(t));
        v[r] = t;
    }
}
static __device__ __forceinline__ void rowred_sum(f32x4& v){
    #pragma unroll
    for (int r = 0; r < 4; r++){
        float t = v[r];
        t += dppmov<0x121>(t);
        t += dppmov<0x122>(t);
        t += dppmov<0x124>(t);
        t += dppmov<0x128>(t);
        v[r] = t;
    }
}

// ---------- K1: weights -> bf16, transposed to [mat][d][c] ----------
__global__ __launch_bounds__(256) void prep_w(const float* __restrict__ w0,
    const float* __restrict__ w1, const float* __restrict__ w2,
    const float* __restrict__ w3, short* __restrict__ wT)
{
    int t = blockIdx.x * 256 + threadIdx.x;        // 4 * 65536 total
    int mat = t >> 16, r = t & 65535, d = r >> 8, c = r & 255;
    const float* src = mat == 0 ? w0 : mat == 1 ? w1 : mat == 2 ? w2 : w3;
    wT[t] = f2bf(src[c * 256 + d]);
}

// ---------- K2: per-pixel GroupNorm (G=32, 8 ch/group), write hn (B, m~=w*64+h, C) bf16 ----------
__global__ __launch_bounds__(256) void gn_kernel(const float* __restrict__ x,
    const float* __restrict__ gnw, const float* __restrict__ gnb,
    short* __restrict__ hn)
{
    int flat = blockIdx.x * 256 + threadIdx.x;     // b*(32*4096) + g*4096 + n
    int n = flat & 4095, g = (flat >> 12) & 31, b = flat >> 17;
    const float* xp = x + (size_t)(b * 256 + g * 8) * 4096 + n;
    float v[8], s = 0.f, s2 = 0.f;
    #pragma unroll
    for (int k = 0; k < 8; k++){ float t = xp[(size_t)k * 4096]; v[k] = t; s += t; s2 += t * t; }
    float mean = s * 0.125f;
    float var  = s2 * 0.125f - mean * mean;
    float inv  = rsqrtf(var + 1e-6f);
    int h = n >> 6, w = n & 63, m = w * 64 + h;    // spatial transpose: column-major index
    short o[8];
    #pragma unroll
    for (int k = 0; k < 8; k++)
        o[k] = f2bf((v[k] - mean) * inv * gnw[g * 8 + k] + gnb[g * 8 + k]);
    *(short8_t*)(hn + (size_t)(b * 4096 + m) * 256 + g * 8) = *(short8_t*)o;
}

// ---------- K3: QKV GEMM. A = hn [16384 x 256], B = wT[mat] (d-major). ----------
__global__ __launch_bounds__(256) void qkv_gemm(const short* __restrict__ hn,
    const short* __restrict__ wT, const float* __restrict__ bq,
    const float* __restrict__ bk, const float* __restrict__ bv,
    short* __restrict__ Q, short* __restrict__ K, short* __restrict__ Vt)
{
    __shared__ short As[64 * 72];
    __shared__ short Bs[64 * 72];
    __shared__ float CT[64 * 65];

    const int tid = threadIdx.x;
    const int m0 = blockIdx.x * 64;
    const int by = blockIdx.y;
    const int mat = by >> 2;                 // 0=Q 1=K 2=V
    const int d0 = (by & 3) * 64;
    const short* w = wT + mat * 65536;
    const float* bias = mat == 0 ? bq : mat == 1 ? bk : bv;

    const int wv = tid >> 6, lane = tid & 63;
    const int wrow = (wv >> 1) * 32, wcol = (wv & 1) * 32;
    const int lrow = lane & 15, lq = lane >> 4;

    f32x4 acc[2][2] = {};

    for (int k0 = 0; k0 < 256; k0 += 64){
        __syncthreads();
        #pragma unroll
        for (int i = 0; i < 2; i++){
            int idx = tid + i * 256, r = idx >> 3, c = (idx & 7) * 8;
            *(short8_t*)&As[r * 72 + c] = *(const short8_t*)(hn + (size_t)(m0 + r) * 256 + k0 + c);
            *(short8_t*)&Bs[r * 72 + c] = *(const short8_t*)(w  + (size_t)(d0 + r) * 256 + k0 + c);
        }
        __syncthreads();
        #pragma unroll
        for (int kk = 0; kk < 2; kk++){
            int off = kk * 32 + lq * 8;
            short8_t a0  = *(short8_t*)&As[(wrow + lrow) * 72 + off];
            short8_t a1  = *(short8_t*)&As[(wrow + 16 + lrow) * 72 + off];
            short8_t b0v = *(short8_t*)&Bs[(wcol + lrow) * 72 + off];
            short8_t b1v = *(short8_t*)&Bs[(wcol + 16 + lrow) * 72 + off];
            acc[0][0] = mfma16(a0, b0v, acc[0][0]);
            acc[0][1] = mfma16(a0, b1v, acc[0][1]);
            acc[1][0] = mfma16(a1, b0v, acc[1][0]);
            acc[1][1] = mfma16(a1, b1v, acc[1][1]);
        }
    }

    if (mat < 2){
        short* out = (mat == 0) ? Q : K;
        #pragma unroll
        for (int i = 0; i < 2; i++)
          #pragma unroll
          for (int j = 0; j < 2; j++)
            #pragma unroll
            for (int r = 0; r < 4; r++){
                int row = wrow + i * 16 + lq * 4 + r;
                int col = wcol + j * 16 + lrow;
                out[(size_t)(m0 + row) * 256 + d0 + col] = f2bf(acc[i][j][r] + bias[d0 + col]);
            }
    } else {
        #pragma unroll
        for (int i = 0; i < 2; i++)
          #pragma unroll
          for (int j = 0; j < 2; j++)
            #pragma unroll
            for (int r = 0; r < 4; r++){
                int row = wrow + i * 16 + lq * 4 + r;
                int col = wcol + j * 16 + lrow;
                CT[col * 65 + row] = acc[i][j][r] + bias[d0 + col];
            }
        __syncthreads();
        int b = m0 >> 12, mloc = m0 & 4095;
        int dr = tid >> 2, wc = (tid & 3) * 16;
        short tmp[16];
        #pragma unroll
        for (int j = 0; j < 16; j++) tmp[j] = f2bf(CT[dr * 65 + wc + j]);
        short* dst = Vt + (size_t)(b * 256 + d0 + dr) * 4096 + mloc + wc;
        *(short8_t*)dst = *(short8_t*)tmp;
        *(short8_t*)(dst + 8) = *(short8_t*)(tmp + 8);
    }
}

// ---------- K4: flash attention — K/V B-frags DIRECT from global, only P via LDS ----------
// block = (pair pr, hh, b): segment 0 = column w=63-pr, segment 1 = column w=pr (65 iters).
// 512 threads / 8 waves: wave = (rowgroup rg2 = wv>>2) x (key colgroup kc = wv&3).
// K prefetched one iter ahead (ping-pong regs); V issued at iter start, consumed post-softmax.
__global__ __launch_bounds__(512, 2) void attn_kernel(const short* __restrict__ Q,
    const short* __restrict__ K, const short* __restrict__ Vt,
    short* __restrict__ hb)
{
    __shared__ short Pls[32 * 72];      // P bf16 [32 q][64 keys], padded (4.5 KB)
    __shared__ float pmaxs[32 * 4];     // per-row per-kc partial max (0.5 KB)

    const int tid = threadIdx.x, lane = tid & 63, wv = tid >> 6;
    const int l15 = lane & 15, lq = lane >> 4;
    const int rg2 = wv >> 2, kc = wv & 3;
    const int b = blockIdx.y;
    const int pr = blockIdx.x >> 1, hh = blockIdx.x & 1;

    const short* Kbase = K  + (size_t)b * 4096 * 256;
    const short* Vbase = Vt + (size_t)b * 256 * 4096;

    // lane-constant offsets (elements)
    const int koff = (kc * 16 + l15) * 256 + lq * 8;          // into K[key][ch]
    int voff[4];
    #pragma unroll
    for (int nt = 0; nt < 4; nt++)
        voff[nt] = (kc * 64 + nt * 16 + l15) * 4096 + lq * 8; // into V^T[ch][m~]

    for (int seg = 0; seg < 2; seg++){
        const int w = (seg == 0) ? (63 - pr) : pr;
        const int q0 = w * 64 + hh * 32;

        // Q fragments in registers
        short8_t qf[8];
        {
            const short* qp = Q + ((size_t)b * 4096 + q0 + rg2 * 16 + l15) * 256;
            #pragma unroll
            for (int ks = 0; ks < 8; ks++)
                qf[ks] = *(const short8_t*)(qp + ks * 32 + lq * 8);
        }
        f32x4 oacc[4] = {};
        float m_reg[4], l_reg[4], al_reg[4];
        #pragma unroll
        for (int r = 0; r < 4; r++){ m_reg[r] = -1e30f; l_reg[r] = 0.f; }

        short8_t kf0[8], kf1[8];
        #pragma unroll
        for (int ks = 0; ks < 8; ks++)
            kf0[ks] = *(const short8_t*)(Kbase + koff + ks * 32);   // tile kb=0

        auto body = [&](short8_t (&kfc)[8], short8_t (&kfn)[8], int kb){
            // V loads for THIS tile (consumed after softmax)
            const short* vit = Vbase + kb * 64;
            short8_t vf[2][4];
            #pragma unroll
            for (int kk = 0; kk < 2; kk++)
                #pragma unroll
                for (int nt = 0; nt < 4; nt++)
                    vf[kk][nt] = *(const short8_t*)(vit + voff[nt] + kk * 32);
            // K prefetch for NEXT tile
            if (kb < w){
                const short* kit = Kbase + (size_t)(kb + 1) * 16384;
                #pragma unroll
                for (int ks = 0; ks < 8; ks++)
                    kfn[ks] = *(const short8_t*)(kit + koff + ks * 32);
            }

            // QK: one 16x16 S tile per wave
            f32x4 s0 = {};
            #pragma unroll
            for (int ks = 0; ks < 8; ks++) s0 = mfma16(qf[ks], kfc[ks], s0);
            #pragma unroll
            for (int r = 0; r < 4; r++) s0[r] *= 0.0625f;

            // per-wave row max (16 lanes) on VALU via DPP
            f32x4 mx = s0;
            rowred_max(mx);
            if (l15 == 0){
                #pragma unroll
                for (int r = 0; r < 4; r++) pmaxs[(rg2 * 16 + lq * 4 + r) * 4 + kc] = mx[r];
            }
            __syncthreads();   // B2: pmaxs ready; also guards Pls WAR vs prev iter's PV

            f32x4 p;
            #pragma unroll
            for (int r = 0; r < 4; r++){
                int row = rg2 * 16 + lq * 4 + r;
                f32x4 pm4 = *(const f32x4*)&pmaxs[row * 4];
                float pm = fmaxf(fmaxf(pm4[0], pm4[1]), fmaxf(pm4[2], pm4[3]));
                float mn = fmaxf(m_reg[r], pm);
                al_reg[r] = exp2f((m_reg[r] - mn) * LOG2E);
                m_reg[r] = mn;
                p[r] = exp2f((s0[r] - mn) * LOG2E);
            }
            #pragma unroll
            for (int r = 0; r < 4; r++)
                Pls[(rg2 * 16 + lq * 4 + r) * 72 + kc * 16 + l15] = f2bf(p[r]);
            f32x4 sm = p;
            rowred_sum(sm);
            #pragma unroll
            for (int r = 0; r < 4; r++){
                l_reg[r] = l_reg[r] * al_reg[r] + sm[r];   // per-kc partial l
                #pragma unroll
                for (int nt = 0; nt < 4; nt++) oacc[nt][r] *= al_reg[r];
            }
            __syncthreads();   // B3: Pls ready

            // PV: wave owns channels kc*64 .. kc*64+64, V frags from regs
            #pragma unroll
            for (int kk = 0; kk < 2; kk++){
                short8_t a = *(short8_t*)&Pls[(rg2 * 16 + l15) * 72 + kk * 32 + lq * 8];
                #pragma unroll
                for (int nt = 0; nt < 4; nt++)
                    oacc[nt] = mfma16(a, vf[kk][nt], oacc[nt]);
            }
        };

        int kb = 0;
        while (true){
            body(kf0, kf1, kb);
            if (++kb > w) break;
            body(kf1, kf0, kb);
            if (++kb > w) break;
        }

        // epilogue: combine per-kc l partials, O /= l, write back in n = h*64 + w order
        __syncthreads();       // last PV done; pmaxs free for reuse as l exchange
        if (l15 == 0){
            #pragma unroll
            for (int r = 0; r < 4; r++) pmaxs[(rg2 * 16 + lq * 4 + r) * 4 + kc] = l_reg[r];
        }
        __syncthreads();
        #pragma unroll
        for (int r = 0; r < 4; r++){
            int row = rg2 * 16 + lq * 4 + r;
            f32x4 l4 = *(const f32x4*)&pmaxs[row * 4];
            float inv = 1.f / (l4[0] + l4[1] + l4[2] + l4[3]);
            int h = hh * 32 + row;
            size_t base = ((size_t)b * 4096 + h * 64 + w) * 256;
            #pragma unroll
            for (int nt = 0; nt < 4; nt++)
                hb[base + kc * 64 + nt * 16 + l15] = f2bf(oacc[nt][r] * inv);
        }
        __syncthreads();       // before next segment reuses Pls/pmaxs
    }
}

// ---------- K5: final proj + bias + residual, coalesced f32 store to (B,C,H,W) ----------
__global__ __launch_bounds__(256) void final_gemm(const short* __restrict__ hbuf,
    const short* __restrict__ wT3, const float* __restrict__ b3,
    const float* __restrict__ x, float* __restrict__ out)
{
    __shared__ short As[64 * 72];
    __shared__ short Bs[64 * 72];
    __shared__ float CT[64 * 65];

    const int tid = threadIdx.x;
    const int m0 = blockIdx.x * 64;        // 64 consecutive n -> fixed h, w = 0..63
    const int d0 = blockIdx.y * 64;
    const int wv = tid >> 6, lane = tid & 63;
    const int wrow = (wv >> 1) * 32, wcol = (wv & 1) * 32;
    const int lrow = lane & 15, lq = lane >> 4;

    f32x4 acc[2][2] = {};
    for (int k0 = 0; k0 < 256; k0 += 64){
        __syncthreads();
        #pragma unroll
        for (int i = 0; i < 2; i++){
            int idx = tid + i * 256, r = idx >> 3, c = (idx & 7) * 8;
            *(short8_t*)&As[r * 72 + c] = *(const short8_t*)(hbuf + (size_t)(m0 + r) * 256 + k0 + c);
            *(short8_t*)&Bs[r * 72 + c] = *(const short8_t*)(wT3 + (size_t)(d0 + r) * 256 + k0 + c);
        }
        __syncthreads();
        #pragma unroll
        for (int kk = 0; kk < 2; kk++){
            int off = kk * 32 + lq * 8;
            short8_t a0  = *(short8_t*)&As[(wrow + lrow) * 72 + off];
            short8_t a1  = *(short8_t*)&As[(wrow + 16 + lrow) * 72 + off];
            short8_t b0v = *(short8_t*)&Bs[(wcol + lrow) * 72 + off];
            short8_t b1v = *(short8_t*)&Bs[(wcol + 16 + lrow) * 72 + off];
            acc[0][0] = mfma16(a0, b0v, acc[0][0]);
            acc[0][1] = mfma16(a0, b1v, acc[0][1]);
            acc[1][0] = mfma16(a1, b0v, acc[1][0]);
            acc[1][1] = mfma16(a1, b1v, acc[1][1]);
        }
    }
    #pragma unroll
    for (int i = 0; i < 2; i++)
      #pragma unroll
      for (int j = 0; j < 2; j++)
        #pragma unroll
        for (int r = 0; r < 4; r++){
            int row = wrow + i * 16 + lq * 4 + r;
            int col = wcol + j * 16 + lrow;
            CT[col * 65 + row] = acc[i][j][r] + b3[d0 + col];
        }
    __syncthreads();
    int b = m0 >> 12, n0 = m0 & 4095, hrow = n0 >> 6;
    int dr = tid >> 2, wc = (tid & 3) * 16;
    size_t base = ((size_t)(b * 256 + d0 + dr) * 64 + hrow) * 64 + wc;
    const f32x4* xp = (const f32x4*)(x + base);
    f32x4* op = (f32x4*)(out + base);
    #pragma unroll
    for (int q = 0; q < 4; q++){
        f32x4 xv = xp[q], o;
        #pragma unroll
        for (int j = 0; j < 4; j++) o[j] = xv[j] + CT[dr * 65 + wc + q * 4 + j];
        op[q] = o;
    }
}

extern "C" void kernel_launch(void* const* d_in, const int* in_sizes, int n_in,
                              void* d_out, int out_size, void* d_ws, size_t ws_size,
                              hipStream_t stream)
{
    const float* x   = (const float*)d_in[0];
    const float* gnw = (const float*)d_in[1];
    const float* gnb = (const float*)d_in[2];
    const float* w0  = (const float*)d_in[3];
    const float* b0  = (const float*)d_in[4];
    const float* w1  = (const float*)d_in[5];
    const float* b1  = (const float*)d_in[6];
    const float* w2  = (const float*)d_in[7];
    const float* b2  = (const float*)d_in[8];
    const float* w3  = (const float*)d_in[9];
    const float* b3  = (const float*)d_in[10];
    float* out = (float*)d_out;

    char* ws = (char*)d_ws;
    short* wT  = (short*)(ws);                  // 4 * 256*256 bf16  = 512 KB
    short* hn  = (short*)(ws + 524288);         // (B, m~, C) bf16   = 8 MB
    short* Qb  = (short*)(ws + 8912896);        // 8 MB
    short* Kb  = (short*)(ws + 17301504);       // 8 MB
    short* Vt  = (short*)(ws + 25690112);       // (B, C, m~) 8 MB
    short* hb  = (short*)(ws + 34078720);       // (B, n, C)  8 MB   (end 40.5 MB)

    prep_w   <<<1024, 256, 0, stream>>>(w0, w1, w2, w3, wT);
    gn_kernel<<<2048, 256, 0, stream>>>(x, gnw, gnb, hn);
    qkv_gemm <<<dim3(256, 12), 256, 0, stream>>>(hn, wT, b0, b1, b2, Qb, Kb, Vt);
    attn_kernel<<<dim3(64, 4), 512, 0, stream>>>(Qb, Kb, Vt, hb);
    final_gemm<<<dim3(256, 4), 256, 0, stream>>>(hb, wT + 3 * 65536, b3, x, out);
}

// Round 6
// 250.508 us; speedup vs baseline: 1.4343x; 1.4343x over previous
//
#include <hip/hip_runtime.h>
#include <math.h>

#define LOG2E 1.4426950408889634f

typedef __attribute__((ext_vector_type(8))) __bf16 bf16x8_t;
typedef __attribute__((ext_vector_type(8))) short short8_t;
typedef __attribute__((ext_vector_type(4))) float f32x4;

static __device__ __forceinline__ short f2bf(float f){
    unsigned u = __builtin_bit_cast(unsigned, f);
    unsigned r = (u + 0x7fffu + ((u >> 16) & 1u)) >> 16;
    return (short)r;
}

static __device__ __forceinline__ f32x4 mfma16(short8_t a, short8_t b, f32x4 c){
    return __builtin_amdgcn_mfma_f32_16x16x32_bf16(
        __builtin_bit_cast(bf16x8_t, a), __builtin_bit_cast(bf16x8_t, b), c, 0, 0, 0);
}

// DPP row-rotate (within 16-lane row) — VALU pipe.
template<int CTRL>
static __device__ __forceinline__ float dppmov(float v){
    return __builtin_bit_cast(float, __builtin_amdgcn_update_dpp(
        0, __builtin_bit_cast(int, v), CTRL, 0xF, 0xF, true));
}
static __device__ __forceinline__ void rowred_max(f32x4& v){
    #pragma unroll
    for (int r = 0; r < 4; r++){
        float t = v[r];
        t = fmaxf(t, dppmov<0x121>(t));
        t = fmaxf(t, dppmov<0x122>(t));
        t = fmaxf(t, dppmov<0x124>(t));
        t = fmaxf(t, dppmov<0x128>(t));
        v[r] = t;
    }
}
static __device__ __forceinline__ void rowred_sum(f32x4& v){
    #pragma unroll
    for (int r = 0; r < 4; r++){
        float t = v[r];
        t += dppmov<0x121>(t);
        t += dppmov<0x122>(t);
        t += dppmov<0x124>(t);
        t += dppmov<0x128>(t);
        v[r] = t;
    }
}

// ---------- K1: weights -> bf16, transposed to [mat][d][c] ----------
__global__ __launch_bounds__(256) void prep_w(const float* __restrict__ w0,
    const float* __restrict__ w1, const float* __restrict__ w2,
    const float* __restrict__ w3, short* __restrict__ wT)
{
    int t = blockIdx.x * 256 + threadIdx.x;        // 4 * 65536 total
    int mat = t >> 16, r = t & 65535, d = r >> 8, c = r & 255;
    const float* src = mat == 0 ? w0 : mat == 1 ? w1 : mat == 2 ? w2 : w3;
    wT[t] = f2bf(src[c * 256 + d]);
}

// ---------- K2: per-pixel GroupNorm (G=32, 8 ch/group), write hn (B, m~=w*64+h, C) bf16 ----------
__global__ __launch_bounds__(256) void gn_kernel(const float* __restrict__ x,
    const float* __restrict__ gnw, const float* __restrict__ gnb,
    short* __restrict__ hn)
{
    int flat = blockIdx.x * 256 + threadIdx.x;     // b*(32*4096) + g*4096 + n
    int n = flat & 4095, g = (flat >> 12) & 31, b = flat >> 17;
    const float* xp = x + (size_t)(b * 256 + g * 8) * 4096 + n;
    float v[8], s = 0.f, s2 = 0.f;
    #pragma unroll
    for (int k = 0; k < 8; k++){ float t = xp[(size_t)k * 4096]; v[k] = t; s += t; s2 += t * t; }
    float mean = s * 0.125f;
    float var  = s2 * 0.125f - mean * mean;
    float inv  = rsqrtf(var + 1e-6f);
    int h = n >> 6, w = n & 63, m = w * 64 + h;    // spatial transpose: column-major index
    short o[8];
    #pragma unroll
    for (int k = 0; k < 8; k++)
        o[k] = f2bf((v[k] - mean) * inv * gnw[g * 8 + k] + gnb[g * 8 + k]);
    *(short8_t*)(hn + (size_t)(b * 4096 + m) * 256 + g * 8) = *(short8_t*)o;
}

// ---------- K3: QKV GEMM. Q row-major; K,V in MFMA-fragment-major layouts. ----------
// Kf[(b,kb,kc,ks,lane,8)]: lane=lq*16+l15 holds key kc*16+l15, ch ks*32+lq*8+j.
// Vf[(b,kb,cg,kk,lane,8)]: lane=lq*16+l15 holds ch cg*16+l15, key kk*32+lq*8+j.
__global__ __launch_bounds__(256) void qkv_gemm(const short* __restrict__ hn,
    const short* __restrict__ wT, const float* __restrict__ bq,
    const float* __restrict__ bk, const float* __restrict__ bv,
    short* __restrict__ Q, short* __restrict__ Kf, short* __restrict__ Vf)
{
    __shared__ short As[64 * 72];
    __shared__ short Bs[64 * 72];
    __shared__ float CT[64 * 65];

    const int tid = threadIdx.x;
    const int m0 = blockIdx.x * 64;
    const int by = blockIdx.y;
    const int mat = by >> 2;                 // 0=Q 1=K 2=V
    const int d0 = (by & 3) * 64;
    const short* w = wT + mat * 65536;
    const float* bias = mat == 0 ? bq : mat == 1 ? bk : bv;

    const int wv = tid >> 6, lane = tid & 63;
    const int wrow = (wv >> 1) * 32, wcol = (wv & 1) * 32;
    const int lrow = lane & 15, lq = lane >> 4;

    f32x4 acc[2][2] = {};

    for (int k0 = 0; k0 < 256; k0 += 64){
        __syncthreads();
        #pragma unroll
        for (int i = 0; i < 2; i++){
            int idx = tid + i * 256, r = idx >> 3, c = (idx & 7) * 8;
            *(short8_t*)&As[r * 72 + c] = *(const short8_t*)(hn + (size_t)(m0 + r) * 256 + k0 + c);
            *(short8_t*)&Bs[r * 72 + c] = *(const short8_t*)(w  + (size_t)(d0 + r) * 256 + k0 + c);
        }
        __syncthreads();
        #pragma unroll
        for (int kk = 0; kk < 2; kk++){
            int off = kk * 32 + lq * 8;
            short8_t a0  = *(short8_t*)&As[(wrow + lrow) * 72 + off];
            short8_t a1  = *(short8_t*)&As[(wrow + 16 + lrow) * 72 + off];
            short8_t b0v = *(short8_t*)&Bs[(wcol + lrow) * 72 + off];
            short8_t b1v = *(short8_t*)&Bs[(wcol + 16 + lrow) * 72 + off];
            acc[0][0] = mfma16(a0, b0v, acc[0][0]);
            acc[0][1] = mfma16(a0, b1v, acc[0][1]);
            acc[1][0] = mfma16(a1, b0v, acc[1][0]);
            acc[1][1] = mfma16(a1, b1v, acc[1][1]);
        }
    }

    const int b = m0 >> 12, kb = (m0 & 4095) >> 6;

    if (mat == 0){
        #pragma unroll
        for (int i = 0; i < 2; i++)
          #pragma unroll
          for (int j = 0; j < 2; j++)
            #pragma unroll
            for (int r = 0; r < 4; r++){
                int row = wrow + i * 16 + lq * 4 + r;
                int col = wcol + j * 16 + lrow;
                Q[(size_t)(m0 + row) * 256 + d0 + col] = f2bf(acc[i][j][r] + bias[d0 + col]);
            }
    } else if (mat == 1){
        // CT[key][ch]
        #pragma unroll
        for (int i = 0; i < 2; i++)
          #pragma unroll
          for (int j = 0; j < 2; j++)
            #pragma unroll
            for (int r = 0; r < 4; r++){
                int row = wrow + i * 16 + lq * 4 + r;
                int col = wcol + j * 16 + lrow;
                CT[row * 65 + col] = acc[i][j][r] + bias[d0 + col];
            }
        __syncthreads();
        int key = tid >> 2, c16 = (tid & 3) * 16;
        int kc = key >> 4, l15 = key & 15;
        #pragma unroll
        for (int half = 0; half < 2; half++){
            int ch0 = c16 + half * 8;                 // local ch base of 8
            int ks = (d0 + ch0) >> 5, lqf = (ch0 & 31) >> 3;
            short tmp[8];
            #pragma unroll
            for (int j = 0; j < 8; j++) tmp[j] = f2bf(CT[key * 65 + ch0 + j]);
            size_t base = ((((size_t)(b * 64 + kb)) * 4 + kc) * 8 + ks) * 512 + (lqf * 16 + l15) * 8;
            *(short8_t*)(Kf + base) = *(short8_t*)tmp;
        }
    } else {
        // CT[ch][key]
        #pragma unroll
        for (int i = 0; i < 2; i++)
          #pragma unroll
          for (int j = 0; j < 2; j++)
            #pragma unroll
            for (int r = 0; r < 4; r++){
                int row = wrow + i * 16 + lq * 4 + r;
                int col = wcol + j * 16 + lrow;
                CT[col * 65 + row] = acc[i][j][r] + bias[d0 + col];
            }
        __syncthreads();
        int dr = tid >> 2, wc = (tid & 3) * 16;       // dr: local ch, wc: local key base
        int ch = d0 + dr, cg = ch >> 4, l15 = ch & 15;
        #pragma unroll
        for (int half = 0; half < 2; half++){
            int k0l = wc + half * 8;
            int kk = k0l >> 5, lqf = (k0l & 31) >> 3;
            short tmp[8];
            #pragma unroll
            for (int j = 0; j < 8; j++) tmp[j] = f2bf(CT[dr * 65 + k0l + j]);
            size_t base = ((((size_t)(b * 64 + kb)) * 16 + cg) * 2 + kk) * 512 + (lqf * 16 + l15) * 8;
            *(short8_t*)(Vf + base) = *(short8_t*)tmp;
        }
    }
}

// ---------- K4: flash attention — frag-major K/V direct from global, only P via LDS ----------
// block = (pair pr, hh, b): segment 0 = column w=63-pr, segment 1 = column w=pr (65 iters).
// 512 threads / 8 waves: wave = (rowgroup rg2 = wv>>2) x (key colgroup kc = wv&3).
__global__ __launch_bounds__(512) void attn_kernel(const short* __restrict__ Q,
    const short* __restrict__ Kf, const short* __restrict__ Vf,
    short* __restrict__ hb)
{
    __shared__ short Pls[32 * 72];      // P bf16 [32 q][64 keys], padded (4.5 KB)
    __shared__ float pmaxs[32 * 4];     // per-row per-kc partial max (0.5 KB)

    const int tid = threadIdx.x, lane = tid & 63, wv = tid >> 6;
    const int l15 = lane & 15, lq = lane >> 4;
    const int rg2 = wv >> 2, kc = wv & 3;
    const int b = blockIdx.y;
    const int pr = blockIdx.x >> 1, hh = blockIdx.x & 1;

    const short* Kb = Kf + (size_t)b * 1048576 + kc * 4096 + lane * 8;   // + kb*16384 + ks*512
    const short* Vb = Vf + (size_t)b * 1048576 + kc * 4096 + lane * 8;   // + kb*16384 + nt*1024 + kk*512

    for (int seg = 0; seg < 2; seg++){
        const int w = (seg == 0) ? (63 - pr) : pr;
        const int q0 = w * 64 + hh * 32;

        // Q fragments in registers
        short8_t qf[8];
        {
            const short* qp = Q + ((size_t)b * 4096 + q0 + rg2 * 16 + l15) * 256;
            #pragma unroll
            for (int ks = 0; ks < 8; ks++)
                qf[ks] = *(const short8_t*)(qp + ks * 32 + lq * 8);
        }
        f32x4 oacc[4] = {};
        float m_reg[4], l_reg[4], al_reg[4];
        #pragma unroll
        for (int r = 0; r < 4; r++){ m_reg[r] = -1e30f; l_reg[r] = 0.f; }

        short8_t kf0[8], kf1[8];
        #pragma unroll
        for (int ks = 0; ks < 8; ks++)
            kf0[ks] = *(const short8_t*)(Kb + ks * 512);   // tile kb=0

        auto body = [&](short8_t (&kfc)[8], short8_t (&kfn)[8], int kb){
            // V frags for THIS tile (consumed after softmax) — coalesced 1KB/inst
            const short* vit = Vb + kb * 16384;
            short8_t vfr[2][4];
            #pragma unroll
            for (int kk = 0; kk < 2; kk++)
                #pragma unroll
                for (int nt = 0; nt < 4; nt++)
                    vfr[kk][nt] = *(const short8_t*)(vit + nt * 1024 + kk * 512);
            // K prefetch for NEXT tile
            if (kb < w){
                const short* kit = Kb + (size_t)(kb + 1) * 16384;
                #pragma unroll
                for (int ks = 0; ks < 8; ks++)
                    kfn[ks] = *(const short8_t*)(kit + ks * 512);
            }

            // QK: one 16x16 S tile per wave
            f32x4 s0 = {};
            #pragma unroll
            for (int ks = 0; ks < 8; ks++) s0 = mfma16(qf[ks], kfc[ks], s0);
            #pragma unroll
            for (int r = 0; r < 4; r++) s0[r] *= 0.0625f;

            // per-wave row max (16 lanes) on VALU via DPP
            f32x4 mx = s0;
            rowred_max(mx);
            if (l15 == 0){
                #pragma unroll
                for (int r = 0; r < 4; r++) pmaxs[(rg2 * 16 + lq * 4 + r) * 4 + kc] = mx[r];
            }
            __syncthreads();   // B2: pmaxs ready; also guards Pls WAR vs prev iter's PV

            f32x4 p;
            #pragma unroll
            for (int r = 0; r < 4; r++){
                int row = rg2 * 16 + lq * 4 + r;
                f32x4 pm4 = *(const f32x4*)&pmaxs[row * 4];
                float pm = fmaxf(fmaxf(pm4[0], pm4[1]), fmaxf(pm4[2], pm4[3]));
                float mn = fmaxf(m_reg[r], pm);
                al_reg[r] = exp2f((m_reg[r] - mn) * LOG2E);
                m_reg[r] = mn;
                p[r] = exp2f((s0[r] - mn) * LOG2E);
            }
            #pragma unroll
            for (int r = 0; r < 4; r++)
                Pls[(rg2 * 16 + lq * 4 + r) * 72 + kc * 16 + l15] = f2bf(p[r]);
            f32x4 sm = p;
            rowred_sum(sm);
            #pragma unroll
            for (int r = 0; r < 4; r++){
                l_reg[r] = l_reg[r] * al_reg[r] + sm[r];   // per-kc partial l
                #pragma unroll
                for (int nt = 0; nt < 4; nt++) oacc[nt][r] *= al_reg[r];
            }
            __syncthreads();   // B3: Pls ready

            // PV: wave owns channels kc*64 .. kc*64+64, V frags from regs
            #pragma unroll
            for (int kk = 0; kk < 2; kk++){
                short8_t a = *(short8_t*)&Pls[(rg2 * 16 + l15) * 72 + kk * 32 + lq * 8];
                #pragma unroll
                for (int nt = 0; nt < 4; nt++)
                    oacc[nt] = mfma16(a, vfr[kk][nt], oacc[nt]);
            }
        };

        int kb = 0;
        while (true){
            body(kf0, kf1, kb);
            if (++kb > w) break;
            body(kf1, kf0, kb);
            if (++kb > w) break;
        }

        // epilogue: combine per-kc l partials, O /= l, write back in n = h*64 + w order
        __syncthreads();       // last PV done; pmaxs free for reuse as l exchange
        if (l15 == 0){
            #pragma unroll
            for (int r = 0; r < 4; r++) pmaxs[(rg2 * 16 + lq * 4 + r) * 4 + kc] = l_reg[r];
        }
        __syncthreads();
        #pragma unroll
        for (int r = 0; r < 4; r++){
            int row = rg2 * 16 + lq * 4 + r;
            f32x4 l4 = *(const f32x4*)&pmaxs[row * 4];
            float inv = 1.f / (l4[0] + l4[1] + l4[2] + l4[3]);
            int h = hh * 32 + row;
            size_t base = ((size_t)b * 4096 + h * 64 + w) * 256;
            #pragma unroll
            for (int nt = 0; nt < 4; nt++)
                hb[base + kc * 64 + nt * 16 + l15] = f2bf(oacc[nt][r] * inv);
        }
        __syncthreads();       // before next segment reuses Pls/pmaxs
    }
}

// ---------- K5: final proj + bias + residual, coalesced f32 store to (B,C,H,W) ----------
__global__ __launch_bounds__(256) void final_gemm(const short* __restrict__ hbuf,
    const short* __restrict__ wT3, const float* __restrict__ b3,
    const float* __restrict__ x, float* __restrict__ out)
{
    __shared__ short As[64 * 72];
    __shared__ short Bs[64 * 72];
    __shared__ float CT[64 * 65];

    const int tid = threadIdx.x;
    const int m0 = blockIdx.x * 64;        // 64 consecutive n -> fixed h, w = 0..63
    const int d0 = blockIdx.y * 64;
    const int wv = tid >> 6, lane = tid & 63;
    const int wrow = (wv >> 1) * 32, wcol = (wv & 1) * 32;
    const int lrow = lane & 15, lq = lane >> 4;

    f32x4 acc[2][2] = {};
    for (int k0 = 0; k0 < 256; k0 += 64){
        __syncthreads();
        #pragma unroll
        for (int i = 0; i < 2; i++){
            int idx = tid + i * 256, r = idx >> 3, c = (idx & 7) * 8;
            *(short8_t*)&As[r * 72 + c] = *(const short8_t*)(hbuf + (size_t)(m0 + r) * 256 + k0 + c);
            *(short8_t*)&Bs[r * 72 + c] = *(const short8_t*)(wT3 + (size_t)(d0 + r) * 256 + k0 + c);
        }
        __syncthreads();
        #pragma unroll
        for (int kk = 0; kk < 2; kk++){
            int off = kk * 32 + lq * 8;
            short8_t a0  = *(short8_t*)&As[(wrow + lrow) * 72 + off];
            short8_t a1  = *(short8_t*)&As[(wrow + 16 + lrow) * 72 + off];
            short8_t b0v = *(short8_t*)&Bs[(wcol + lrow) * 72 + off];
            short8_t b1v = *(short8_t*)&Bs[(wcol + 16 + lrow) * 72 + off];
            acc[0][0] = mfma16(a0, b0v, acc[0][0]);
            acc[0][1] = mfma16(a0, b1v, acc[0][1]);
            acc[1][0] = mfma16(a1, b0v, acc[1][0]);
            acc[1][1] = mfma16(a1, b1v, acc[1][1]);
        }
    }
    #pragma unroll
    for (int i = 0; i < 2; i++)
      #pragma unroll
      for (int j = 0; j < 2; j++)
        #pragma unroll
        for (int r = 0; r < 4; r++){
            int row = wrow + i * 16 + lq * 4 + r;
            int col = wcol + j * 16 + lrow;
            CT[col * 65 + row] = acc[i][j][r] + b3[d0 + col];
        }
    __syncthreads();
    int b = m0 >> 12, n0 = m0 & 4095, hrow = n0 >> 6;
    int dr = tid >> 2, wc = (tid & 3) * 16;
    size_t base = ((size_t)(b * 256 + d0 + dr) * 64 + hrow) * 64 + wc;
    const f32x4* xp = (const f32x4*)(x + base);
    f32x4* op = (f32x4*)(out + base);
    #pragma unroll
    for (int q = 0; q < 4; q++){
        f32x4 xv = xp[q], o;
        #pragma unroll
        for (int j = 0; j < 4; j++) o[j] = xv[j] + CT[dr * 65 + wc + q * 4 + j];
        op[q] = o;
    }
}

extern "C" void kernel_launch(void* const* d_in, const int* in_sizes, int n_in,
                              void* d_out, int out_size, void* d_ws, size_t ws_size,
                              hipStream_t stream)
{
    const float* x   = (const float*)d_in[0];
    const float* gnw = (const float*)d_in[1];
    const float* gnb = (const float*)d_in[2];
    const float* w0  = (const float*)d_in[3];
    const float* b0  = (const float*)d_in[4];
    const float* w1  = (const float*)d_in[5];
    const float* b1  = (const float*)d_in[6];
    const float* w2  = (const float*)d_in[7];
    const float* b2  = (const float*)d_in[8];
    const float* w3  = (const float*)d_in[9];
    const float* b3  = (const float*)d_in[10];
    float* out = (float*)d_out;

    char* ws = (char*)d_ws;
    short* wT  = (short*)(ws);                  // 4 * 256*256 bf16  = 512 KB
    short* hn  = (short*)(ws + 524288);         // (B, m~, C) bf16   = 8 MB
    short* Qb  = (short*)(ws + 8912896);        // 8 MB
    short* Kfb = (short*)(ws + 17301504);       // frag-major K, 8 MB
    short* Vfb = (short*)(ws + 25690112);       // frag-major V, 8 MB
    short* hb  = (short*)(ws + 34078720);       // (B, n, C)  8 MB   (end 40.5 MB)

    prep_w   <<<1024, 256, 0, stream>>>(w0, w1, w2, w3, wT);
    gn_kernel<<<2048, 256, 0, stream>>>(x, gnw, gnb, hn);
    qkv_gemm <<<dim3(256, 12), 256, 0, stream>>>(hn, wT, b0, b1, b2, Qb, Kfb, Vfb);
    attn_kernel<<<dim3(64, 4), 512, 0, stream>>>(Qb, Kfb, Vfb, hb);
    final_gemm<<<dim3(256, 4), 256, 0, stream>>>(hb, wT + 3 * 65536, b3, x, out);
}

// Round 7
// 246.718 us; speedup vs baseline: 1.4564x; 1.0154x over previous
//
#include <hip/hip_runtime.h>
#include <math.h>

#define LOG2E 1.4426950408889634f

typedef __attribute__((ext_vector_type(8))) __bf16 bf16x8_t;
typedef __attribute__((ext_vector_type(8))) short short8_t;
typedef __attribute__((ext_vector_type(4))) float f32x4;

static __device__ __forceinline__ short f2bf(float f){
    unsigned u = __builtin_bit_cast(unsigned, f);
    unsigned r = (u + 0x7fffu + ((u >> 16) & 1u)) >> 16;
    return (short)r;
}

static __device__ __forceinline__ f32x4 mfma16(short8_t a, short8_t b, f32x4 c){
    return __builtin_amdgcn_mfma_f32_16x16x32_bf16(
        __builtin_bit_cast(bf16x8_t, a), __builtin_bit_cast(bf16x8_t, b), c, 0, 0, 0);
}

// DPP row-rotate (within 16-lane row) — VALU pipe.
template<int CTRL>
static __device__ __forceinline__ float dppmov(float v){
    return __builtin_bit_cast(float, __builtin_amdgcn_update_dpp(
        0, __builtin_bit_cast(int, v), CTRL, 0xF, 0xF, true));
}
static __device__ __forceinline__ void rowred_max(f32x4& v){
    #pragma unroll
    for (int r = 0; r < 4; r++){
        float t = v[r];
        t = fmaxf(t, dppmov<0x121>(t));
        t = fmaxf(t, dppmov<0x122>(t));
        t = fmaxf(t, dppmov<0x124>(t));
        t = fmaxf(t, dppmov<0x128>(t));
        v[r] = t;
    }
}
static __device__ __forceinline__ void rowred_sum(f32x4& v){
    #pragma unroll
    for (int r = 0; r < 4; r++){
        float t = v[r];
        t += dppmov<0x121>(t);
        t += dppmov<0x122>(t);
        t += dppmov<0x124>(t);
        t += dppmov<0x128>(t);
        v[r] = t;
    }
}

// ---------- K1: weights -> bf16, transposed to [mat][d][c], coalesced via LDS tile ----------
__global__ __launch_bounds__(256) void prep_w(const float* __restrict__ w0,
    const float* __restrict__ w1, const float* __restrict__ w2,
    const float* __restrict__ w3, short* __restrict__ wT)
{
    __shared__ float T[64 * 65];
    const int mat = blockIdx.x >> 4, tile = blockIdx.x & 15;
    const int c0 = (tile >> 2) * 64, d0 = (tile & 3) * 64;
    const float* src = mat == 0 ? w0 : mat == 1 ? w1 : mat == 2 ? w2 : w3;
    const int t = threadIdx.x;
    // read coalesced: rows are c, cols are d
    #pragma unroll
    for (int i = 0; i < 4; i++){
        int r = (t >> 4) + i * 16, c4 = (t & 15) * 4;
        f32x4 v = *(const f32x4*)(src + (size_t)(c0 + r) * 256 + d0 + c4);
        #pragma unroll
        for (int j = 0; j < 4; j++) T[r * 65 + c4 + j] = v[j];
    }
    __syncthreads();
    // write coalesced: rows are d, cols are c
    int drow = t >> 2, cb = (t & 3) * 16;
    short tmp[16];
    #pragma unroll
    for (int j = 0; j < 16; j++) tmp[j] = f2bf(T[(cb + j) * 65 + drow]);
    short* dst = wT + (size_t)mat * 65536 + (size_t)(d0 + drow) * 256 + c0 + cb;
    *(short8_t*)dst = *(short8_t*)tmp;
    *(short8_t*)(dst + 8) = *(short8_t*)(tmp + 8);
}

// ---------- K2: per-pixel GroupNorm (G=32, 8 ch/group), write hn (B, m~=w*64+h, C) bf16 ----------
__global__ __launch_bounds__(256) void gn_kernel(const float* __restrict__ x,
    const float* __restrict__ gnw, const float* __restrict__ gnb,
    short* __restrict__ hn)
{
    int flat = blockIdx.x * 256 + threadIdx.x;     // b*(32*4096) + g*4096 + n
    int n = flat & 4095, g = (flat >> 12) & 31, b = flat >> 17;
    const float* xp = x + (size_t)(b * 256 + g * 8) * 4096 + n;
    float v[8], s = 0.f, s2 = 0.f;
    #pragma unroll
    for (int k = 0; k < 8; k++){ float t = xp[(size_t)k * 4096]; v[k] = t; s += t; s2 += t * t; }
    float mean = s * 0.125f;
    float var  = s2 * 0.125f - mean * mean;
    float inv  = rsqrtf(var + 1e-6f);
    int h = n >> 6, w = n & 63, m = w * 64 + h;    // spatial transpose: column-major index
    short o[8];
    #pragma unroll
    for (int k = 0; k < 8; k++)
        o[k] = f2bf((v[k] - mean) * inv * gnw[g * 8 + k] + gnb[g * 8 + k]);
    *(short8_t*)(hn + (size_t)(b * 4096 + m) * 256 + g * 8) = *(short8_t*)o;
}

// ---------- K3: QKV GEMM. Q row-major (pre-scaled by 1/16); K,V fragment-major. ----------
// Kf[(b,kb,kc,ks,lane,8)]: lane=lq*16+l15 holds key kc*16+l15, ch ks*32+lq*8+j.
// Vf[(b,kb,cg,kk,lane,8)]: lane=lq*16+l15 holds ch cg*16+l15, key kk*32+lq*8+j.
__global__ __launch_bounds__(256) void qkv_gemm(const short* __restrict__ hn,
    const short* __restrict__ wT, const float* __restrict__ bq,
    const float* __restrict__ bk, const float* __restrict__ bv,
    short* __restrict__ Q, short* __restrict__ Kf, short* __restrict__ Vf)
{
    __shared__ short As[64 * 72];
    __shared__ short Bs[64 * 72];
    __shared__ float CT[64 * 65];

    const int tid = threadIdx.x;
    const int m0 = blockIdx.x * 64;
    const int by = blockIdx.y;
    const int mat = by >> 2;                 // 0=Q 1=K 2=V
    const int d0 = (by & 3) * 64;
    const short* w = wT + mat * 65536;
    const float* bias = mat == 0 ? bq : mat == 1 ? bk : bv;

    const int wv = tid >> 6, lane = tid & 63;
    const int wrow = (wv >> 1) * 32, wcol = (wv & 1) * 32;
    const int lrow = lane & 15, lq = lane >> 4;

    f32x4 acc[2][2] = {};

    for (int k0 = 0; k0 < 256; k0 += 64){
        __syncthreads();
        #pragma unroll
        for (int i = 0; i < 2; i++){
            int idx = tid + i * 256, r = idx >> 3, c = (idx & 7) * 8;
            *(short8_t*)&As[r * 72 + c] = *(const short8_t*)(hn + (size_t)(m0 + r) * 256 + k0 + c);
            *(short8_t*)&Bs[r * 72 + c] = *(const short8_t*)(w  + (size_t)(d0 + r) * 256 + k0 + c);
        }
        __syncthreads();
        #pragma unroll
        for (int kk = 0; kk < 2; kk++){
            int off = kk * 32 + lq * 8;
            short8_t a0  = *(short8_t*)&As[(wrow + lrow) * 72 + off];
            short8_t a1  = *(short8_t*)&As[(wrow + 16 + lrow) * 72 + off];
            short8_t b0v = *(short8_t*)&Bs[(wcol + lrow) * 72 + off];
            short8_t b1v = *(short8_t*)&Bs[(wcol + 16 + lrow) * 72 + off];
            acc[0][0] = mfma16(a0, b0v, acc[0][0]);
            acc[0][1] = mfma16(a0, b1v, acc[0][1]);
            acc[1][0] = mfma16(a1, b0v, acc[1][0]);
            acc[1][1] = mfma16(a1, b1v, acc[1][1]);
        }
    }

    const int b = m0 >> 12, kb = (m0 & 4095) >> 6;

    if (mat == 0){
        #pragma unroll
        for (int i = 0; i < 2; i++)
          #pragma unroll
          for (int j = 0; j < 2; j++)
            #pragma unroll
            for (int r = 0; r < 4; r++){
                int row = wrow + i * 16 + lq * 4 + r;
                int col = wcol + j * 16 + lrow;
                Q[(size_t)(m0 + row) * 256 + d0 + col] = f2bf((acc[i][j][r] + bias[d0 + col]) * 0.0625f);
            }
    } else if (mat == 1){
        // CT[key][ch]
        #pragma unroll
        for (int i = 0; i < 2; i++)
          #pragma unroll
          for (int j = 0; j < 2; j++)
            #pragma unroll
            for (int r = 0; r < 4; r++){
                int row = wrow + i * 16 + lq * 4 + r;
                int col = wcol + j * 16 + lrow;
                CT[row * 65 + col] = acc[i][j][r] + bias[d0 + col];
            }
        __syncthreads();
        int key = tid >> 2, c16 = (tid & 3) * 16;
        int kc = key >> 4, l15 = key & 15;
        #pragma unroll
        for (int half = 0; half < 2; half++){
            int ch0 = c16 + half * 8;                 // local ch base of 8
            int ks = (d0 + ch0) >> 5, lqf = (ch0 & 31) >> 3;
            short tmp[8];
            #pragma unroll
            for (int j = 0; j < 8; j++) tmp[j] = f2bf(CT[key * 65 + ch0 + j]);
            size_t base = ((((size_t)(b * 64 + kb)) * 4 + kc) * 8 + ks) * 512 + (lqf * 16 + l15) * 8;
            *(short8_t*)(Kf + base) = *(short8_t*)tmp;
        }
    } else {
        // CT[ch][key]
        #pragma unroll
        for (int i = 0; i < 2; i++)
          #pragma unroll
          for (int j = 0; j < 2; j++)
            #pragma unroll
            for (int r = 0; r < 4; r++){
                int row = wrow + i * 16 + lq * 4 + r;
                int col = wcol + j * 16 + lrow;
                CT[col * 65 + row] = acc[i][j][r] + bias[d0 + col];
            }
        __syncthreads();
        int dr = tid >> 2, wc = (tid & 3) * 16;       // dr: local ch, wc: local key base
        int ch = d0 + dr, cg = ch >> 4, l15 = ch & 15;
        #pragma unroll
        for (int half = 0; half < 2; half++){
            int k0l = wc + half * 8;
            int kk = k0l >> 5, lqf = (k0l & 31) >> 3;
            short tmp[8];
            #pragma unroll
            for (int j = 0; j < 8; j++) tmp[j] = f2bf(CT[dr * 65 + k0l + j]);
            size_t base = ((((size_t)(b * 64 + kb)) * 16 + cg) * 2 + kk) * 512 + (lqf * 16 + l15) * 8;
            *(short8_t*)(Vf + base) = *(short8_t*)tmp;
        }
    }
}

// ---------- K4: flash attention — frag-major K/V from global, only P via LDS ----------
// 512 blocks (2/CU), one column each; linear-id mapping pairs l and l+256 with
// complementary columns (w, 63-w) so each CU's two resident blocks sum to 65 iters.
// 512 threads / 8 waves: wave = (rowgroup rg2 = wv>>2) x (key colgroup kc = wv&3).
__global__ __launch_bounds__(512) void attn_kernel(const short* __restrict__ Q,
    const short* __restrict__ Kf, const short* __restrict__ Vf,
    short* __restrict__ hb)
{
    __shared__ short Pls[32 * 72];      // P bf16 [32 q][64 keys], padded (4.5 KB)
    __shared__ float pmaxs[32 * 4];     // per-row per-kc partial max (0.5 KB)

    const int tid = threadIdx.x, lane = tid & 63, wv = tid >> 6;
    const int l15 = lane & 15, lq = lane >> 4;
    const int rg2 = wv >> 2, kc = wv & 3;

    // decode (b, w, hh) from linear block id; l and l+256 get complementary w
    const int lid = blockIdx.x;
    const int hi = lid >> 8, u = lid & 255;
    const int w  = hi ? 63 - (u >> 2) : (u >> 2);
    const int hh = u & 1;
    const int b  = ((u >> 1) & 1) | (hi << 1);
    const int q0 = w * 64 + hh * 32;

    const short* Kb = Kf + (size_t)b * 1048576 + kc * 4096 + lane * 8;   // + kb*16384 + ks*512
    const short* Vb = Vf + (size_t)b * 1048576 + kc * 4096 + lane * 8;   // + kb*16384 + nt*1024 + kk*512

    // Q fragments in registers (Q pre-scaled by 1/16)
    short8_t qf[8];
    {
        const short* qp = Q + ((size_t)b * 4096 + q0 + rg2 * 16 + l15) * 256;
        #pragma unroll
        for (int ks = 0; ks < 8; ks++)
            qf[ks] = *(const short8_t*)(qp + ks * 32 + lq * 8);
    }
    f32x4 oacc[4] = {};
    float m_reg[4], l_reg[4], al_reg[4];
    #pragma unroll
    for (int r = 0; r < 4; r++){ m_reg[r] = -1e30f; l_reg[r] = 0.f; }

    short8_t kf0[8], kf1[8];
    #pragma unroll
    for (int ks = 0; ks < 8; ks++)
        kf0[ks] = *(const short8_t*)(Kb + ks * 512);   // tile kb=0

    auto body = [&](short8_t (&kfc)[8], short8_t (&kfn)[8], int kb){
        // V frags for THIS tile (consumed after softmax) — coalesced 1KB/inst
        const short* vit = Vb + kb * 16384;
        short8_t vfr[2][4];
        #pragma unroll
        for (int kk = 0; kk < 2; kk++)
            #pragma unroll
            for (int nt = 0; nt < 4; nt++)
                vfr[kk][nt] = *(const short8_t*)(vit + nt * 1024 + kk * 512);
        // K prefetch for NEXT tile
        if (kb < w){
            const short* kit = Kb + (size_t)(kb + 1) * 16384;
            #pragma unroll
            for (int ks = 0; ks < 8; ks++)
                kfn[ks] = *(const short8_t*)(kit + ks * 512);
        }

        // QK: one 16x16 S tile per wave (scale folded into Q)
        f32x4 s0 = {};
        #pragma unroll
        for (int ks = 0; ks < 8; ks++) s0 = mfma16(qf[ks], kfc[ks], s0);

        // per-wave row max (16 lanes) on VALU via DPP
        f32x4 mx = s0;
        rowred_max(mx);
        if (l15 == 0){
            #pragma unroll
            for (int r = 0; r < 4; r++) pmaxs[(rg2 * 16 + lq * 4 + r) * 4 + kc] = mx[r];
        }
        __syncthreads();   // B2: pmaxs ready; also guards Pls WAR vs prev iter's PV

        f32x4 p;
        #pragma unroll
        for (int r = 0; r < 4; r++){
            int row = rg2 * 16 + lq * 4 + r;
            f32x4 pm4 = *(const f32x4*)&pmaxs[row * 4];
            float pm = fmaxf(fmaxf(pm4[0], pm4[1]), fmaxf(pm4[2], pm4[3]));
            float mn = fmaxf(m_reg[r], pm);
            al_reg[r] = exp2f((m_reg[r] - mn) * LOG2E);
            m_reg[r] = mn;
            p[r] = exp2f((s0[r] - mn) * LOG2E);
        }
        #pragma unroll
        for (int r = 0; r < 4; r++)
            Pls[(rg2 * 16 + lq * 4 + r) * 72 + kc * 16 + l15] = f2bf(p[r]);
        f32x4 sm = p;
        rowred_sum(sm);
        #pragma unroll
        for (int r = 0; r < 4; r++){
            l_reg[r] = l_reg[r] * al_reg[r] + sm[r];   // per-kc partial l
            #pragma unroll
            for (int nt = 0; nt < 4; nt++) oacc[nt][r] *= al_reg[r];
        }
        __syncthreads();   // B3: Pls ready

        // PV: wave owns channels kc*64 .. kc*64+64, V frags from regs
        #pragma unroll
        for (int kk = 0; kk < 2; kk++){
            short8_t a = *(short8_t*)&Pls[(rg2 * 16 + l15) * 72 + kk * 32 + lq * 8];
            #pragma unroll
            for (int nt = 0; nt < 4; nt++)
                oacc[nt] = mfma16(a, vfr[kk][nt], oacc[nt]);
        }
    };

    int kb = 0;
    while (true){
        body(kf0, kf1, kb);
        if (++kb > w) break;
        body(kf1, kf0, kb);
        if (++kb > w) break;
    }

    // epilogue: combine per-kc l partials, O /= l, write back in n = h*64 + w order
    __syncthreads();       // last PV done; pmaxs free for reuse as l exchange
    if (l15 == 0){
        #pragma unroll
        for (int r = 0; r < 4; r++) pmaxs[(rg2 * 16 + lq * 4 + r) * 4 + kc] = l_reg[r];
    }
    __syncthreads();
    #pragma unroll
    for (int r = 0; r < 4; r++){
        int row = rg2 * 16 + lq * 4 + r;
        f32x4 l4 = *(const f32x4*)&pmaxs[row * 4];
        float inv = 1.f / (l4[0] + l4[1] + l4[2] + l4[3]);
        int h = hh * 32 + row;
        size_t base = ((size_t)b * 4096 + h * 64 + w) * 256;
        #pragma unroll
        for (int nt = 0; nt < 4; nt++)
            hb[base + kc * 64 + nt * 16 + l15] = f2bf(oacc[nt][r] * inv);
    }
}

// ---------- K5: final proj + bias + residual, coalesced f32 store to (B,C,H,W) ----------
__global__ __launch_bounds__(256) void final_gemm(const short* __restrict__ hbuf,
    const short* __restrict__ wT3, const float* __restrict__ b3,
    const float* __restrict__ x, float* __restrict__ out)
{
    __shared__ short As[64 * 72];
    __shared__ short Bs[64 * 72];
    __shared__ float CT[64 * 65];

    const int tid = threadIdx.x;
    const int m0 = blockIdx.x * 64;        // 64 consecutive n -> fixed h, w = 0..63
    const int d0 = blockIdx.y * 64;
    const int wv = tid >> 6, lane = tid & 63;
    const int wrow = (wv >> 1) * 32, wcol = (wv & 1) * 32;
    const int lrow = lane & 15, lq = lane >> 4;

    f32x4 acc[2][2] = {};
    for (int k0 = 0; k0 < 256; k0 += 64){
        __syncthreads();
        #pragma unroll
        for (int i = 0; i < 2; i++){
            int idx = tid + i * 256, r = idx >> 3, c = (idx & 7) * 8;
            *(short8_t*)&As[r * 72 + c] = *(const short8_t*)(hbuf + (size_t)(m0 + r) * 256 + k0 + c);
            *(short8_t*)&Bs[r * 72 + c] = *(const short8_t*)(wT3 + (size_t)(d0 + r) * 256 + k0 + c);
        }
        __syncthreads();
        #pragma unroll
        for (int kk = 0; kk < 2; kk++){
            int off = kk * 32 + lq * 8;
            short8_t a0  = *(short8_t*)&As[(wrow + lrow) * 72 + off];
            short8_t a1  = *(short8_t*)&As[(wrow + 16 + lrow) * 72 + off];
            short8_t b0v = *(short8_t*)&Bs[(wcol + lrow) * 72 + off];
            short8_t b1v = *(short8_t*)&Bs[(wcol + 16 + lrow) * 72 + off];
            acc[0][0] = mfma16(a0, b0v, acc[0][0]);
            acc[0][1] = mfma16(a0, b1v, acc[0][1]);
            acc[1][0] = mfma16(a1, b0v, acc[1][0]);
            acc[1][1] = mfma16(a1, b1v, acc[1][1]);
        }
    }
    #pragma unroll
    for (int i = 0; i < 2; i++)
      #pragma unroll
      for (int j = 0; j < 2; j++)
        #pragma unroll
        for (int r = 0; r < 4; r++){
            int row = wrow + i * 16 + lq * 4 + r;
            int col = wcol + j * 16 + lrow;
            CT[col * 65 + row] = acc[i][j][r] + b3[d0 + col];
        }
    __syncthreads();
    int b = m0 >> 12, n0 = m0 & 4095, hrow = n0 >> 6;
    int dr = tid >> 2, wc = (tid & 3) * 16;
    size_t base = ((size_t)(b * 256 + d0 + dr) * 64 + hrow) * 64 + wc;
    const f32x4* xp = (const f32x4*)(x + base);
    f32x4* op = (f32x4*)(out + base);
    #pragma unroll
    for (int q = 0; q < 4; q++){
        f32x4 xv = xp[q], o;
        #pragma unroll
        for (int j = 0; j < 4; j++) o[j] = xv[j] + CT[dr * 65 + wc + q * 4 + j];
        op[q] = o;
    }
}

extern "C" void kernel_launch(void* const* d_in, const int* in_sizes, int n_in,
                              void* d_out, int out_size, void* d_ws, size_t ws_size,
                              hipStream_t stream)
{
    const float* x   = (const float*)d_in[0];
    const float* gnw = (const float*)d_in[1];
    const float* gnb = (const float*)d_in[2];
    const float* w0  = (const float*)d_in[3];
    const float* b0  = (const float*)d_in[4];
    const float* w1  = (const float*)d_in[5];
    const float* b1  = (const float*)d_in[6];
    const float* w2  = (const float*)d_in[7];
    const float* b2  = (const float*)d_in[8];
    const float* w3  = (const float*)d_in[9];
    const float* b3  = (const float*)d_in[10];
    float* out = (float*)d_out;

    char* ws = (char*)d_ws;
    short* wT  = (short*)(ws);                  // 4 * 256*256 bf16  = 512 KB
    short* hn  = (short*)(ws + 524288);         // (B, m~, C) bf16   = 8 MB
    short* Qb  = (short*)(ws + 8912896);        // 8 MB
    short* Kfb = (short*)(ws + 17301504);       // frag-major K, 8 MB
    short* Vfb = (short*)(ws + 25690112);       // frag-major V, 8 MB
    short* hb  = (short*)(ws + 34078720);       // (B, n, C)  8 MB   (end 40.5 MB)

    prep_w   <<<64, 256, 0, stream>>>(w0, w1, w2, w3, wT);
    gn_kernel<<<2048, 256, 0, stream>>>(x, gnw, gnb, hn);
    qkv_gemm <<<dim3(256, 12), 256, 0, stream>>>(hn, wT, b0, b1, b2, Qb, Kfb, Vfb);
    attn_kernel<<<512, 512, 0, stream>>>(Qb, Kfb, Vfb, hb);
    final_gemm<<<dim3(256, 4), 256, 0, stream>>>(hb, wT + 3 * 65536, b3, x, out);
}

// Round 8
// 230.271 us; speedup vs baseline: 1.5604x; 1.0714x over previous
//
#include <hip/hip_runtime.h>
#include <math.h>

#define LOG2E 1.4426950408889634f

typedef __attribute__((ext_vector_type(8))) __bf16 bf16x8_t;
typedef __attribute__((ext_vector_type(8))) short short8_t;
typedef __attribute__((ext_vector_type(4))) short short4_t;
typedef __attribute__((ext_vector_type(4))) float f32x4;

static __device__ __forceinline__ short f2bf(float f){
    unsigned u = __builtin_bit_cast(unsigned, f);
    unsigned r = (u + 0x7fffu + ((u >> 16) & 1u)) >> 16;
    return (short)r;
}

static __device__ __forceinline__ f32x4 mfma16(short8_t a, short8_t b, f32x4 c){
    return __builtin_amdgcn_mfma_f32_16x16x32_bf16(
        __builtin_bit_cast(bf16x8_t, a), __builtin_bit_cast(bf16x8_t, b), c, 0, 0, 0);
}

// xor-lane16 within 32-lane halves (BitMode swizzle), xor-lane32 via bpermute
static __device__ __forceinline__ float swz16(float v){
    return __builtin_bit_cast(float,
        __builtin_amdgcn_ds_swizzle(__builtin_bit_cast(int, v), 0x401F));
}
static __device__ __forceinline__ float bperm32(int addr, float v){
    return __builtin_bit_cast(float,
        __builtin_amdgcn_ds_bpermute(addr, __builtin_bit_cast(int, v)));
}
// per-query (lane&15) reduction over a wave's 16-key strip: regs + xor16 + xor32
static __device__ __forceinline__ float redmax16(f32x4 v, int a32){
    float t = fmaxf(fmaxf(v[0], v[1]), fmaxf(v[2], v[3]));
    t = fmaxf(t, swz16(t));
    t = fmaxf(t, bperm32(a32, t));
    return t;
}
static __device__ __forceinline__ float redsum16(f32x4 v, int a32){
    float t = (v[0] + v[1]) + (v[2] + v[3]);
    t += swz16(t);
    t += bperm32(a32, t);
    return t;
}

// ---------- K1: weights -> bf16, transposed to [mat][d][c], coalesced via LDS tile ----------
__global__ __launch_bounds__(256) void prep_w(const float* __restrict__ w0,
    const float* __restrict__ w1, const float* __restrict__ w2,
    const float* __restrict__ w3, short* __restrict__ wT)
{
    __shared__ float T[64 * 65];
    const int mat = blockIdx.x >> 4, tile = blockIdx.x & 15;
    const int c0 = (tile >> 2) * 64, d0 = (tile & 3) * 64;
    const float* src = mat == 0 ? w0 : mat == 1 ? w1 : mat == 2 ? w2 : w3;
    const int t = threadIdx.x;
    #pragma unroll
    for (int i = 0; i < 4; i++){
        int r = (t >> 4) + i * 16, c4 = (t & 15) * 4;
        f32x4 v = *(const f32x4*)(src + (size_t)(c0 + r) * 256 + d0 + c4);
        #pragma unroll
        for (int j = 0; j < 4; j++) T[r * 65 + c4 + j] = v[j];
    }
    __syncthreads();
    int drow = t >> 2, cb = (t & 3) * 16;
    short tmp[16];
    #pragma unroll
    for (int j = 0; j < 16; j++) tmp[j] = f2bf(T[(cb + j) * 65 + drow]);
    short* dst = wT + (size_t)mat * 65536 + (size_t)(d0 + drow) * 256 + c0 + cb;
    *(short8_t*)dst = *(short8_t*)tmp;
    *(short8_t*)(dst + 8) = *(short8_t*)(tmp + 8);
}

// ---------- K2: per-pixel GroupNorm (G=32, 8 ch/group), write hn (B, m~=w*64+h, C) bf16 ----------
__global__ __launch_bounds__(256) void gn_kernel(const float* __restrict__ x,
    const float* __restrict__ gnw, const float* __restrict__ gnb,
    short* __restrict__ hn)
{
    int flat = blockIdx.x * 256 + threadIdx.x;
    int n = flat & 4095, g = (flat >> 12) & 31, b = flat >> 17;
    const float* xp = x + (size_t)(b * 256 + g * 8) * 4096 + n;
    float v[8], s = 0.f, s2 = 0.f;
    #pragma unroll
    for (int k = 0; k < 8; k++){ float t = xp[(size_t)k * 4096]; v[k] = t; s += t; s2 += t * t; }
    float mean = s * 0.125f;
    float var  = s2 * 0.125f - mean * mean;
    float inv  = rsqrtf(var + 1e-6f);
    int h = n >> 6, w = n & 63, m = w * 64 + h;
    short o[8];
    #pragma unroll
    for (int k = 0; k < 8; k++)
        o[k] = f2bf((v[k] - mean) * inv * gnw[g * 8 + k] + gnb[g * 8 + k]);
    *(short8_t*)(hn + (size_t)(b * 4096 + m) * 256 + g * 8) = *(short8_t*)o;
}

// ---------- K3: QKV GEMM. Q row-major (pre-scaled 1/16); K,V fragment-major. ----------
// Kf[(b,kb64,kc,ks,lane,8)]: lane holds key kc*16+(lane&15), ch ks*32+(lane>>4)*8+j.
// Vf2[(b,kbd,kc,cht,lane,8)]: lane holds ch cht*16+(lane&15); j<4: key kbd*128+kc*16+(lane>>4)*4+j,
//                             j>=4: key kbd*128+64+kc*16+(lane>>4)*4+(j-4).  (K=32 PV permutation)
__global__ __launch_bounds__(256) void qkv_gemm(const short* __restrict__ hn,
    const short* __restrict__ wT, const float* __restrict__ bq,
    const float* __restrict__ bk, const float* __restrict__ bv,
    short* __restrict__ Q, short* __restrict__ Kf, short* __restrict__ Vf)
{
    __shared__ short As[64 * 72];
    __shared__ short Bs[64 * 72];
    __shared__ float CT[64 * 65];

    const int tid = threadIdx.x;
    const int m0 = blockIdx.x * 64;
    const int by = blockIdx.y;
    const int mat = by >> 2;                 // 0=Q 1=K 2=V
    const int d0 = (by & 3) * 64;
    const short* w = wT + mat * 65536;
    const float* bias = mat == 0 ? bq : mat == 1 ? bk : bv;

    const int wv = tid >> 6, lane = tid & 63;
    const int wrow = (wv >> 1) * 32, wcol = (wv & 1) * 32;
    const int lrow = lane & 15, lq = lane >> 4;

    f32x4 acc[2][2] = {};

    for (int k0 = 0; k0 < 256; k0 += 64){
        __syncthreads();
        #pragma unroll
        for (int i = 0; i < 2; i++){
            int idx = tid + i * 256, r = idx >> 3, c = (idx & 7) * 8;
            *(short8_t*)&As[r * 72 + c] = *(const short8_t*)(hn + (size_t)(m0 + r) * 256 + k0 + c);
            *(short8_t*)&Bs[r * 72 + c] = *(const short8_t*)(w  + (size_t)(d0 + r) * 256 + k0 + c);
        }
        __syncthreads();
        #pragma unroll
        for (int kk = 0; kk < 2; kk++){
            int off = kk * 32 + lq * 8;
            short8_t a0  = *(short8_t*)&As[(wrow + lrow) * 72 + off];
            short8_t a1  = *(short8_t*)&As[(wrow + 16 + lrow) * 72 + off];
            short8_t b0v = *(short8_t*)&Bs[(wcol + lrow) * 72 + off];
            short8_t b1v = *(short8_t*)&Bs[(wcol + 16 + lrow) * 72 + off];
            acc[0][0] = mfma16(a0, b0v, acc[0][0]);
            acc[0][1] = mfma16(a0, b1v, acc[0][1]);
            acc[1][0] = mfma16(a1, b0v, acc[1][0]);
            acc[1][1] = mfma16(a1, b1v, acc[1][1]);
        }
    }

    const int b = m0 >> 12, kb64 = (m0 & 4095) >> 6;

    if (mat == 0){
        #pragma unroll
        for (int i = 0; i < 2; i++)
          #pragma unroll
          for (int j = 0; j < 2; j++)
            #pragma unroll
            for (int r = 0; r < 4; r++){
                int row = wrow + i * 16 + lq * 4 + r;
                int col = wcol + j * 16 + lrow;
                Q[(size_t)(m0 + row) * 256 + d0 + col] = f2bf((acc[i][j][r] + bias[d0 + col]) * 0.0625f);
            }
    } else if (mat == 1){
        // CT[key][ch]
        #pragma unroll
        for (int i = 0; i < 2; i++)
          #pragma unroll
          for (int j = 0; j < 2; j++)
            #pragma unroll
            for (int r = 0; r < 4; r++){
                int row = wrow + i * 16 + lq * 4 + r;
                int col = wcol + j * 16 + lrow;
                CT[row * 65 + col] = acc[i][j][r] + bias[d0 + col];
            }
        __syncthreads();
        int key = tid >> 2, c16 = (tid & 3) * 16;
        int kc = key >> 4, l15 = key & 15;
        #pragma unroll
        for (int half = 0; half < 2; half++){
            int ch0 = c16 + half * 8;
            int ks = (d0 + ch0) >> 5, lqf = (ch0 & 31) >> 3;
            short tmp[8];
            #pragma unroll
            for (int j = 0; j < 8; j++) tmp[j] = f2bf(CT[key * 65 + ch0 + j]);
            size_t base = ((((size_t)(b * 64 + kb64)) * 4 + kc) * 8 + ks) * 512 + (lqf * 16 + l15) * 8;
            *(short8_t*)(Kf + base) = *(short8_t*)tmp;
        }
    } else {
        // CT[ch][key]
        #pragma unroll
        for (int i = 0; i < 2; i++)
          #pragma unroll
          for (int j = 0; j < 2; j++)
            #pragma unroll
            for (int r = 0; r < 4; r++){
                int row = wrow + i * 16 + lq * 4 + r;
                int col = wcol + j * 16 + lrow;
                CT[col * 65 + row] = acc[i][j][r] + bias[d0 + col];
            }
        __syncthreads();
        // write Vf2: this block covers kbd = kb64>>1 half (parity = kb64&1), ch d0..d0+64
        const int kbd = kb64 >> 1, parity = kb64 & 1;
        const int cht_l = tid >> 6, lane_s = tid & 63;
        const int l15s = lane_s & 15, lg4s = lane_s >> 4;
        const int cht = (d0 >> 4) + cht_l;
        #pragma unroll
        for (int kc = 0; kc < 4; kc++){
            short tmp[4];
            #pragma unroll
            for (int j = 0; j < 4; j++)
                tmp[j] = f2bf(CT[(cht_l * 16 + l15s) * 65 + kc * 16 + lg4s * 4 + j]);
            size_t base = (size_t)b * 1048576 + (size_t)kbd * 32768 + kc * 8192
                        + cht * 512 + lane_s * 8 + parity * 4;
            *(short4_t*)(Vf + base) = *(short4_t*)tmp;
        }
    }
}

// ---------- K4: barrier-free flash attention ----------
// 1024 blocks of 256 threads (4 waves). Block = (quad q=id>>8 -> b; c=id&255: w6=c>>2,
// hh=(c>>1)&1, rg=c&1; w = (q&1)? 63-w6 : w6). Each wave (kc) runs an independent
// online-softmax chain over its 16-key strips (S^T trick: stats per lane-column),
// accumulating O^T over all 256 ch. Two-tile pairing -> K=32 PV. End: 2-barrier combine.
__global__ __launch_bounds__(256, 2) void attn_kernel(const short* __restrict__ Q,
    const short* __restrict__ Kf, const short* __restrict__ Vf,
    short* __restrict__ hb)
{
    __shared__ float mls[4][16][2];
    __shared__ float LO[4][16][260];     // [kc][q][ch] f32, padded

    const int tid = threadIdx.x, lane = tid & 63, kc = tid >> 6;
    const int l15 = lane & 15, lg4 = lane >> 4;
    const int a32 = ((lane ^ 32) << 2);

    const int id = blockIdx.x;
    const int qd = id >> 8, c = id & 255;
    const int w6 = c >> 2, hh = (c >> 1) & 1, rg = c & 1;
    const int b  = qd;
    const int w  = (qd & 1) ? 63 - w6 : w6;
    const int q0 = w * 64 + hh * 32 + rg * 16;

    const short* Kb = Kf + (size_t)b * 1048576 + kc * 4096 + lane * 8;   // +kb*16384 +ks*512
    const short* Vb = Vf + (size_t)b * 1048576 + kc * 8192 + lane * 8;   // +kbd*32768 +cht*512

    // Q as B-fragment (pre-scaled): lane holds Q[q0+l15][ks*32+lg4*8 ..+8]
    short8_t qf[8];
    {
        const short* qp = Q + ((size_t)b * 4096 + q0 + l15) * 256;
        #pragma unroll
        for (int ks = 0; ks < 8; ks++)
            qf[ks] = *(const short8_t*)(qp + ks * 32 + lg4 * 8);
    }

    f32x4 oacc[16] = {};                 // O^T partial: 16 ch-tiles x f32x4
    float m_run = -1e30f, l_run = 0.f;

    short8_t kcur[8], knext[8];
    #pragma unroll
    for (int ks = 0; ks < 8; ks++)
        kcur[ks] = *(const short8_t*)(Kb + ks * 512);

    for (int kb = 0; kb <= w; kb += 2){
        const bool has_odd = (kb + 1 <= w);
        if (has_odd){
            const short* kit = Kb + (size_t)(kb + 1) * 16384;
            #pragma unroll
            for (int ks = 0; ks < 8; ks++)
                knext[ks] = *(const short8_t*)(kit + ks * 512);
        }
        // even tile: S^T = K (A) x Q (B)
        f32x4 st = {};
        #pragma unroll
        for (int ks = 0; ks < 8; ks++) st = mfma16(kcur[ks], qf[ks], st);
        float mloc = redmax16(st, a32);
        float m_e = fmaxf(m_run, mloc);
        float alpha_e = exp2f((m_run - m_e) * LOG2E);
        f32x4 p_e;
        #pragma unroll
        for (int r = 0; r < 4; r++) p_e[r] = exp2f((st[r] - m_e) * LOG2E);
        l_run = l_run * alpha_e + redsum16(p_e, a32);

        f32x4 p_o = {};
        float alpha_o = 1.f;
        if (has_odd){
            if (kb + 2 <= w){
                const short* kit = Kb + (size_t)(kb + 2) * 16384;
                #pragma unroll
                for (int ks = 0; ks < 8; ks++)
                    kcur[ks] = *(const short8_t*)(kit + ks * 512);
            }
            f32x4 st2 = {};
            #pragma unroll
            for (int ks = 0; ks < 8; ks++) st2 = mfma16(knext[ks], qf[ks], st2);
            float mloc2 = redmax16(st2, a32);
            float m_o = fmaxf(m_e, mloc2);
            alpha_o = exp2f((m_e - m_o) * LOG2E);
            #pragma unroll
            for (int r = 0; r < 4; r++) p_o[r] = exp2f((st2[r] - m_o) * LOG2E);
            l_run = l_run * alpha_o + redsum16(p_o, a32);
            #pragma unroll
            for (int r = 0; r < 4; r++) p_e[r] *= alpha_o;
            m_run = m_o;
        } else {
            m_run = m_e;
        }

        // pack P^T pair as B-fragment (K=32, key-permuted to match Vf2)
        short pb[8];
        #pragma unroll
        for (int r = 0; r < 4; r++){ pb[r] = f2bf(p_e[r]); pb[4 + r] = f2bf(p_o[r]); }
        short8_t pbf = *(short8_t*)pb;
        float apair = alpha_e * alpha_o;

        // PV: O^T[cht] = apair*O^T[cht] + V^T-frag x P^T
        const short* vit = Vb + (size_t)(kb >> 1) * 32768;
        #pragma unroll
        for (int cht = 0; cht < 16; cht++){
            short8_t vfr = *(const short8_t*)(vit + cht * 512);
            f32x4 t = oacc[cht];
            #pragma unroll
            for (int r = 0; r < 4; r++) t[r] *= apair;
            oacc[cht] = mfma16(vfr, pbf, t);
        }
    }

    // ---- combine the 4 kc partials ----
    if (lg4 == 0){ mls[kc][l15][0] = m_run; mls[kc][l15][1] = l_run; }
    __syncthreads();
    float m0v = mls[0][l15][0], m1v = mls[1][l15][0], m2v = mls[2][l15][0], m3v = mls[3][l15][0];
    float mstar = fmaxf(fmaxf(m0v, m1v), fmaxf(m2v, m3v));
    float Lsum = mls[0][l15][1] * exp2f((m0v - mstar) * LOG2E)
               + mls[1][l15][1] * exp2f((m1v - mstar) * LOG2E)
               + mls[2][l15][1] * exp2f((m2v - mstar) * LOG2E)
               + mls[3][l15][1] * exp2f((m3v - mstar) * LOG2E);
    float sc = exp2f((m_run - mstar) * LOG2E);
    #pragma unroll
    for (int cht = 0; cht < 16; cht++){
        f32x4 t = oacc[cht];
        #pragma unroll
        for (int r = 0; r < 4; r++) t[r] *= sc;
        *(f32x4*)&LO[kc][l15][cht * 16 + lg4 * 4] = t;
    }
    __syncthreads();
    // sum across kc; wave kc handles ch quarter kc*64..+64; lane: q=l15, ch0=kc*64+lg4*16
    {
        const int ch0 = kc * 64 + lg4 * 16;
        float inv = 1.f / Lsum;
        f32x4 s4[4];
        #pragma unroll
        for (int c4 = 0; c4 < 4; c4++){
            f32x4 s = *(const f32x4*)&LO[0][l15][ch0 + c4 * 4];
            #pragma unroll
            for (int kcj = 1; kcj < 4; kcj++){
                f32x4 t = *(const f32x4*)&LO[kcj][l15][ch0 + c4 * 4];
                #pragma unroll
                for (int r = 0; r < 4; r++) s[r] += t[r];
            }
            #pragma unroll
            for (int r = 0; r < 4; r++) s[r] *= inv;
            s4[c4] = s;
        }
        short tmp[16];
        #pragma unroll
        for (int c4 = 0; c4 < 4; c4++)
            #pragma unroll
            for (int r = 0; r < 4; r++) tmp[c4 * 4 + r] = f2bf(s4[c4][r]);
        const int h = hh * 32 + rg * 16 + l15;
        short* dst = hb + ((size_t)b * 4096 + h * 64 + w) * 256 + ch0;
        *(short8_t*)dst = *(short8_t*)tmp;
        *(short8_t*)(dst + 8) = *(short8_t*)(tmp + 8);
    }
}

// ---------- K5: final proj + bias + residual, coalesced f32 store to (B,C,H,W) ----------
__global__ __launch_bounds__(256) void final_gemm(const short* __restrict__ hbuf,
    const short* __restrict__ wT3, const float* __restrict__ b3,
    const float* __restrict__ x, float* __restrict__ out)
{
    __shared__ short As[64 * 72];
    __shared__ short Bs[64 * 72];
    __shared__ float CT[64 * 65];

    const int tid = threadIdx.x;
    const int m0 = blockIdx.x * 64;
    const int d0 = blockIdx.y * 64;
    const int wv = tid >> 6, lane = tid & 63;
    const int wrow = (wv >> 1) * 32, wcol = (wv & 1) * 32;
    const int lrow = lane & 15, lq = lane >> 4;

    f32x4 acc[2][2] = {};
    for (int k0 = 0; k0 < 256; k0 += 64){
        __syncthreads();
        #pragma unroll
        for (int i = 0; i < 2; i++){
            int idx = tid + i * 256, r = idx >> 3, c = (idx & 7) * 8;
            *(short8_t*)&As[r * 72 + c] = *(const short8_t*)(hbuf + (size_t)(m0 + r) * 256 + k0 + c);
            *(short8_t*)&Bs[r * 72 + c] = *(const short8_t*)(wT3 + (size_t)(d0 + r) * 256 + k0 + c);
        }
        __syncthreads();
        #pragma unroll
        for (int kk = 0; kk < 2; kk++){
            int off = kk * 32 + lq * 8;
            short8_t a0  = *(short8_t*)&As[(wrow + lrow) * 72 + off];
            short8_t a1  = *(short8_t*)&As[(wrow + 16 + lrow) * 72 + off];
            short8_t b0v = *(short8_t*)&Bs[(wcol + lrow) * 72 + off];
            short8_t b1v = *(short8_t*)&Bs[(wcol + 16 + lrow) * 72 + off];
            acc[0][0] = mfma16(a0, b0v, acc[0][0]);
            acc[0][1] = mfma16(a0, b1v, acc[0][1]);
            acc[1][0] = mfma16(a1, b0v, acc[1][0]);
            acc[1][1] = mfma16(a1, b1v, acc[1][1]);
        }
    }
    #pragma unroll
    for (int i = 0; i < 2; i++)
      #pragma unroll
      for (int j = 0; j < 2; j++)
        #pragma unroll
        for (int r = 0; r < 4; r++){
            int row = wrow + i * 16 + lq * 4 + r;
            int col = wcol + j * 16 + lrow;
            CT[col * 65 + row] = acc[i][j][r] + b3[d0 + col];
        }
    __syncthreads();
    int b = m0 >> 12, n0 = m0 & 4095, hrow = n0 >> 6;
    int dr = tid >> 2, wc = (tid & 3) * 16;
    size_t base = ((size_t)(b * 256 + d0 + dr) * 64 + hrow) * 64 + wc;
    const f32x4* xp = (const f32x4*)(x + base);
    f32x4* op = (f32x4*)(out + base);
    #pragma unroll
    for (int q = 0; q < 4; q++){
        f32x4 xv = xp[q], o;
        #pragma unroll
        for (int j = 0; j < 4; j++) o[j] = xv[j] + CT[dr * 65 + wc + q * 4 + j];
        op[q] = o;
    }
}

extern "C" void kernel_launch(void* const* d_in, const int* in_sizes, int n_in,
                              void* d_out, int out_size, void* d_ws, size_t ws_size,
                              hipStream_t stream)
{
    const float* x   = (const float*)d_in[0];
    const float* gnw = (const float*)d_in[1];
    const float* gnb = (const float*)d_in[2];
    const float* w0  = (const float*)d_in[3];
    const float* b0  = (const float*)d_in[4];
    const float* w1  = (const float*)d_in[5];
    const float* b1  = (const float*)d_in[6];
    const float* w2  = (const float*)d_in[7];
    const float* b2  = (const float*)d_in[8];
    const float* w3  = (const float*)d_in[9];
    const float* b3  = (const float*)d_in[10];
    float* out = (float*)d_out;

    char* ws = (char*)d_ws;
    short* wT  = (short*)(ws);                  // 512 KB
    short* hn  = (short*)(ws + 524288);         // 8 MB
    short* Qb  = (short*)(ws + 8912896);        // 8 MB
    short* Kfb = (short*)(ws + 17301504);       // frag-major K, 8 MB
    short* Vfb = (short*)(ws + 25690112);       // frag-major V (K=32 perm), 8 MB
    short* hb  = (short*)(ws + 34078720);       // (B, n, C) 8 MB

    prep_w   <<<64, 256, 0, stream>>>(w0, w1, w2, w3, wT);
    gn_kernel<<<2048, 256, 0, stream>>>(x, gnw, gnb, hn);
    qkv_gemm <<<dim3(256, 12), 256, 0, stream>>>(hn, wT, b0, b1, b2, Qb, Kfb, Vfb);
    attn_kernel<<<1024, 256, 0, stream>>>(Qb, Kfb, Vfb, hb);
    final_gemm<<<dim3(256, 4), 256, 0, stream>>>(hb, wT + 3 * 65536, b3, x, out);
}